// Round 2
// baseline (513.181 us; speedup 1.0000x reference)
//
#include <hip/hip_runtime.h>
#include <math.h>

// Problem constants
#define GG 16
#define NNODE 512
#define EEDGE 2048
#define KEEPN 256
#define PITERS 64
#define NNT 8192    // G*N
#define NET 32768   // G*E

// workspace float offsets
#define WS_C1N 0
#define WS_C2N 8192
#define WS_BN  16384
#define WS_SN  24576
#define WS_C1E 32768
#define WS_C2E 65536
#define WS_BE  98304
#define WS_SE  131072
#define WS_MASK 163840   // int[8192]
#define WS_KEEP 172032   // int[32768]
#define WS_KLIST 204800  // int[32768]
#define WS_KCNT 237568   // int[16]
#define WS_SCALE 237584  // float[16]

// output float offsets: xn | L0 | xe | L1
#define O_XN 0
#define O_L0 524288
#define O_XE 4718592
#define O_L1 6815744

// zero-space: float4 indices over concatenated L0 (4,194,304 f) || L1 (67,108,864 f)
#define L04 1048576      // float4 count of L0
#define ZTOT4 17825792   // total float4 to zero
#define ZB1 7340032      // K1 zeroes [0, ZB1)
#define ZB2 14680064     // K2 zeroes [ZB1, ZB2); K3 zeroes [ZB2, ZTOT4)

__device__ __forceinline__ void zero_range(float* __restrict__ out, int lo, int hi,
                                           int start, int stride) {
  float4 z = make_float4(0.f, 0.f, 0.f, 0.f);
  float4* o4 = (float4*)out;
  for (int i = lo + start; i < hi; i += stride) {
    int f = (i < L04) ? (O_L0 / 4 + i) : (O_L1 / 4 + (i - L04));
    o4[f] = z;
  }
}

// ---------------------------------------------------------------------------
// K1: per-row channel dots (one wave per row) + zero-fill chunk 1.
__global__ __launch_bounds__(256) void k_dots(const float* __restrict__ xn,
    const float* __restrict__ xe, const float* __restrict__ Wn,
    const float* __restrict__ We, float* __restrict__ ws, float* __restrict__ out) {
  if (blockIdx.x >= 10240) {
    zero_range(out, 0, ZB1, (blockIdx.x - 10240) * 256 + threadIdx.x, 262144);
    return;
  }
  int gw = (blockIdx.x * 256 + threadIdx.x) >> 6;
  int lane = threadIdx.x & 63;
  const float* x; const float* W; int row; float *c1, *c2, *bs;
  if (gw < NNT) {
    row = gw; x = xn + (size_t)row * 64; W = Wn;
    c1 = ws + WS_C1N; c2 = ws + WS_C2N; bs = ws + WS_BN;
  } else {
    row = gw - NNT;
    x = xe + (size_t)row * 64; W = We;
    c1 = ws + WS_C1E; c2 = ws + WS_C2E; bs = ws + WS_BE;
  }
  float v = x[lane];
  float r0 = v * W[lane];
  float r1 = v * W[64 + lane];
  float r2 = v * W[128 + lane];
  for (int o = 32; o; o >>= 1) {
    r0 += __shfl_xor(r0, o, 64);
    r1 += __shfl_xor(r1, o, 64);
    r2 += __shfl_xor(r2, o, 64);
  }
  if (lane == 0) { c1[row] = r1; c2[row] = r2; bs[row] = r0 + r1 + r2; }
}

// ---------------------------------------------------------------------------
// K2: per-graph two-hop message passing, LDS-privatized, fused score compute.
// Blocks 0..15 = node graphs, 16..31 = edge graphs, 32.. = zero-fill chunk 2.
__global__ __launch_bounds__(256) void k_msg(
    const int* __restrict__ src_n, const int* __restrict__ dst_n, const float* __restrict__ wn,
    const int* __restrict__ src_e, const int* __restrict__ dst_e, const float* __restrict__ we,
    const float* __restrict__ bnp, const float* __restrict__ bep,
    float* __restrict__ ws, float* __restrict__ out) {
  if (blockIdx.x >= 32) {
    zero_range(out, ZB1, ZB2, (blockIdx.x - 32) * 256 + threadIdx.x, 262144);
    return;
  }
  __shared__ float sm[5 * 2048];   // 40 KB: c1|c2|d1|d2|e2 (node blocks use first 512 each)
  float* c1 = sm;
  float* c2 = sm + 2048;
  float* d1 = sm + 4096;
  float* d2 = sm + 6144;
  float* e2 = sm + 8192;
  const int tid = threadIdx.x;
  const bool isNode = blockIdx.x < 16;
  const int g = isNode ? blockIdx.x : blockIdx.x - 16;
  const int n = isNode ? NNODE : EEDGE;
  const int roff = g * n;
  const float* C1 = ws + (isNode ? WS_C1N : WS_C1E) + roff;
  const float* C2 = ws + (isNode ? WS_C2N : WS_C2E) + roff;
  const float* BB = ws + (isNode ? WS_BN : WS_BE) + roff;
  float* S = ws + (isNode ? WS_SN : WS_SE) + roff;
  const float bias = isNode ? bnp[0] : bep[0];
  const int ecnt = isNode ? 4096 : 8192;
  const int* SA = isNode ? src_n : src_e;
  const int* DA = isNode ? dst_n : dst_e;
  const float* WA = isNode ? wn : we;

  for (int i = tid; i < n; i += 256) {
    c1[i] = C1[i]; c2[i] = C2[i]; d1[i] = 0.f; d2[i] = 0.f; e2[i] = 0.f;
  }
  __syncthreads();
  // hop 1: d1 = L c1, d2 = L c2
  for (int t = tid; t < ecnt; t += 256) {
    int idx = isNode ? ((t < 2048) ? g * 2048 + t : 32768 + g * 2048 + (t - 2048))
                     : g * 8192 + t;
    int s = SA[idx] - roff, d = DA[idx] - roff;
    float w = WA[idx];
    atomicAdd(&d1[d], w * c1[s]);
    atomicAdd(&d2[d], w * c2[s]);
  }
  __syncthreads();
  // hop 2: e2 = L d2
  for (int t = tid; t < ecnt; t += 256) {
    int idx = isNode ? ((t < 2048) ? g * 2048 + t : 32768 + g * 2048 + (t - 2048))
                     : g * 8192 + t;
    int s = SA[idx] - roff, d = DA[idx] - roff;
    float w = WA[idx];
    atomicAdd(&e2[d], w * d2[s]);
  }
  __syncthreads();
  // scores: sigmoid(base - d1 - 2 d2 + 0.5 e2 + bias)
  for (int i = tid; i < n; i += 256) {
    float t = BB[i] - d1[i] - 2.0f * d2[i] + 0.5f * e2[i] + bias;
    S[i] = 1.0f / (1.0f + expf(-t));
  }
}

// ---------------------------------------------------------------------------
// K3: per-graph pooling (blocks 0..15): aug -> bitonic top-256 -> keep_e ->
// CSR -> 64 power iterations -> scale. Blocks 16.. = zero-fill chunk 3.
__global__ __launch_bounds__(512) void k_pool(
    const int* __restrict__ edge_u, const int* __restrict__ edge_v,
    float* __restrict__ ws, float* __restrict__ out) {
  const int tid = threadIdx.x;
  if (blockIdx.x >= 16) {
    zero_range(out, ZB2, ZTOT4, (blockIdx.x - 16) * 512 + tid, 262144);
    return;
  }
  const int g = blockIdx.x;
  __shared__ float aug[NNODE];
  __shared__ float key[NNODE];
  __shared__ int kidx[NNODE];
  __shared__ int su[EEDGE];
  __shared__ int sv[EEDGE];
  __shared__ int maskS[NNODE];
  __shared__ int degS[NNODE];
  __shared__ int offS[NNODE];
  __shared__ int adj[2 * EEDGE];
  __shared__ float wv[NNODE];
  __shared__ float red[8];
  __shared__ int kcnt;
  int* wsi = (int*)ws;

  int nidx = g * NNODE + tid;
  aug[tid] = ws[WS_SN + nidx];
  for (int e = tid; e < EEDGE; e += 512) {
    su[e] = edge_u[g * EEDGE + e];
    sv[e] = edge_v[g * EEDGE + e];
  }
  if (tid == 0) kcnt = 0;
  maskS[tid] = 0;
  __syncthreads();
  for (int e = tid; e < EEDGE; e += 512) {
    float s = ws[WS_SE + g * EEDGE + e];
    atomicAdd(&aug[su[e]], s);
    atomicAdd(&aug[sv[e]], s);
  }
  __syncthreads();
  // bitonic sort 512: descending by value, ascending index on ties
  key[tid] = aug[tid]; kidx[tid] = tid;
  __syncthreads();
  for (int k = 2; k <= NNODE; k <<= 1) {
    for (int j = k >> 1; j > 0; j >>= 1) {
      int i = tid, ixj = i ^ j;
      if (ixj > i) {
        float ka = key[i], kb = key[ixj];
        int ia = kidx[i], ib = kidx[ixj];
        bool aAfter = (ka < kb) || (ka == kb && ia > ib);
        bool doswap = ((i & k) == 0) ? aAfter : !aAfter;
        if (doswap) { key[i] = kb; key[ixj] = ka; kidx[i] = ib; kidx[ixj] = ia; }
      }
      __syncthreads();
    }
  }
  if (tid < KEEPN) maskS[kidx[tid]] = 1;
  degS[tid] = 0;
  __syncthreads();
  wsi[WS_MASK + nidx] = maskS[tid];
  for (int e = tid; e < EEDGE; e += 512) {
    int k = maskS[su[e]] & maskS[sv[e]];
    wsi[WS_KEEP + g * EEDGE + e] = k;
    if (k) {
      int p = atomicAdd(&kcnt, 1);
      wsi[WS_KLIST + g * EEDGE + p] = e;
      atomicAdd(&degS[su[e]], 1);
      atomicAdd(&degS[sv[e]], 1);
    }
  }
  __syncthreads();
  if (tid == 0) wsi[WS_KCNT + g] = kcnt;
  // exclusive prefix of deg -> offS
  int* t0 = (int*)key;
  t0[tid] = degS[tid];
  __syncthreads();
  for (int s = 1; s < NNODE; s <<= 1) {
    int v = t0[tid] + ((tid >= s) ? t0[tid - s] : 0);
    __syncthreads();
    t0[tid] = v;
    __syncthreads();
  }
  offS[tid] = t0[tid] - degS[tid];
  __syncthreads();
  for (int e = tid; e < EEDGE; e += 512) {
    if (maskS[su[e]] & maskS[sv[e]]) {
      int pu = atomicAdd(&offS[su[e]], 1); adj[pu] = sv[e];
      int pv = atomicAdd(&offS[sv[e]], 1); adj[pv] = su[e];
    }
  }
  __syncthreads();
  int myDeg = degS[tid];
  int myEnd = offS[tid];
  int myStart = myEnd - myDeg;
  const int lane = tid & 63;
  const int wvid = tid >> 6;
  wv[tid] = 0.04419417382415922f; // 1/sqrt(512)
  __syncthreads();
  for (int it = 0; it < PITERS; ++it) {
    float acc = (float)myDeg * wv[tid];
    for (int p = myStart; p < myEnd; ++p) acc -= wv[adj[p]];
    float sq = acc * acc;
    for (int o = 32; o; o >>= 1) sq += __shfl_xor(sq, o, 64);
    if (lane == 0) red[wvid] = sq;
    __syncthreads();
    float tot = red[0] + red[1] + red[2] + red[3] + red[4] + red[5] + red[6] + red[7];
    float rn = 1.0f / (sqrtf(tot) + 1e-12f);
    wv[tid] = acc * rn;
    __syncthreads();
  }
  {
    float acc = (float)myDeg * wv[tid];
    for (int p = myStart; p < myEnd; ++p) acc -= wv[adj[p]];
    float pr = wv[tid] * acc;
    for (int o = 32; o; o >>= 1) pr += __shfl_xor(pr, o, 64);
    if (lane == 0) red[wvid] = pr;
    __syncthreads();
    if (tid == 0) {
      float lam = red[0] + red[1] + red[2] + red[3] + red[4] + red[5] + red[6] + red[7];
      ws[WS_SCALE + g] = 2.0f / (lam + 1e-12f);
    }
  }
}

// ---------------------------------------------------------------------------
// K4: outputs. [0,512) xn dense; [512,2560) xe dense; [2560,2576) L0 scatter;
// [2576,6672) L1 pair enumeration over compacted kept edges.
__global__ __launch_bounds__(256) void k_out(
    const float* __restrict__ xn, const float* __restrict__ xe,
    const int* __restrict__ edge_u, const int* __restrict__ edge_v,
    const float* __restrict__ ws, float* __restrict__ out) {
  int b = blockIdx.x, tid = threadIdx.x;
  const int* wsi = (const int*)ws;
  if (b < 512) {
    int idx = b * 256 + tid;
    int row = idx >> 4;
    float s = ws[WS_SN + row] * (float)wsi[WS_MASK + row];
    float4 x4 = ((const float4*)xn)[idx];
    ((float4*)(out + O_XN))[idx] = make_float4(x4.x * s, x4.y * s, x4.z * s, x4.w * s);
  } else if (b < 2560) {
    int idx = (b - 512) * 256 + tid;
    int row = idx >> 4;
    float s = ws[WS_SE + row] * (float)wsi[WS_KEEP + row];
    float4 x4 = ((const float4*)xe)[idx];
    ((float4*)(out + O_XE))[idx] = make_float4(x4.x * s, x4.y * s, x4.z * s, x4.w * s);
  } else if (b < 2576) {
    int g = b - 2560;
    int cnt = wsi[WS_KCNT + g];
    float s = ws[WS_SCALE + g];
    float* L0 = out + O_L0 + (long long)g * (NNODE * NNODE);
    const int* kl = wsi + WS_KLIST + g * EEDGE;
    const int* eu = edge_u + g * EEDGE;
    const int* ev = edge_v + g * EEDGE;
    for (int t = tid; t < cnt; t += 256) {
      int e = kl[t];
      int u = eu[e], v = ev[e];
      atomicAdd(&L0[u * NNODE + u], s);
      atomicAdd(&L0[v * NNODE + v], s);
      atomicAdd(&L0[u * NNODE + v], -s);
      atomicAdd(&L0[v * NNODE + u], -s);
    }
  } else {
    int q = b - 2576;
    int g = q >> 8, sb = q & 255;
    int cnt = wsi[WS_KCNT + g];
    float s = ws[WS_SCALE + g];
    float* L1 = out + O_L1 + (long long)g * (EEDGE * EEDGE);
    const int* kl = wsi + WS_KLIST + g * EEDGE;
    const int* eu = edge_u + g * EEDGE;
    const int* ev = edge_v + g * EEDGE;
    for (int a = sb; a < cnt; a += 256) {
      int e1 = kl[a];
      int u1 = eu[e1], v1 = ev[e1];
      long long rowoff = (long long)e1 * EEDGE;
      for (int b2 = tid; b2 < cnt; b2 += 256) {
        int e2 = kl[b2];
        int u2 = eu[e2], v2 = ev[e2];
        int val = (u1 == u2) + (v1 == v2) - (v1 == u2) - (u1 == v2);
        if (val) L1[rowoff + e2] = s * (float)val;
      }
    }
  }
}

// ---------------------------------------------------------------------------
extern "C" void kernel_launch(void* const* d_in, const int* in_sizes, int n_in,
                              void* d_out, int out_size, void* d_ws, size_t ws_size,
                              hipStream_t stream) {
  const float* x_n = (const float*)d_in[0];
  const float* x_e = (const float*)d_in[1];
  const int* edge_u = (const int*)d_in[2];
  const int* edge_v = (const int*)d_in[3];
  const int* src_n = (const int*)d_in[4];
  const int* dst_n = (const int*)d_in[5];
  const float* ew_n = (const float*)d_in[6];
  const int* src_e = (const int*)d_in[7];
  const int* dst_e = (const int*)d_in[8];
  const float* ew_e = (const float*)d_in[9];
  const float* W_n = (const float*)d_in[10];
  const float* b_n = (const float*)d_in[11];
  const float* W_e = (const float*)d_in[12];
  const float* b_e = (const float*)d_in[13];
  float* ws = (float*)d_ws;
  float* out = (float*)d_out;

  // K1: channel dots (10240 blocks) + zero chunk 1 (1024 blocks)
  k_dots<<<10240 + 1024, 256, 0, stream>>>(x_n, x_e, W_n, W_e, ws, out);
  // K2: per-graph LDS two-hop message passing + scores (32) + zero chunk 2 (1024)
  k_msg<<<32 + 1024, 256, 0, stream>>>(src_n, dst_n, ew_n, src_e, dst_e, ew_e,
                                       b_n, b_e, ws, out);
  // K3: pooling (16) + zero chunk 3 (512)
  k_pool<<<16 + 512, 512, 0, stream>>>(edge_u, edge_v, ws, out);
  // K4: dense xn/xe + sparse L0/L1 scatter
  k_out<<<6672, 256, 0, stream>>>(x_n, x_e, edge_u, edge_v, ws, out);
}

// Round 3
// 481.675 us; speedup vs baseline: 1.0654x; 1.0654x over previous
//
#include <hip/hip_runtime.h>
#include <math.h>

// Problem constants
#define GG 16
#define NNODE 512
#define EEDGE 2048
#define KEEPN 256
#define PITERS 64
#define NNT 8192    // G*N
#define NET 32768   // G*E

// workspace float offsets
#define WS_C1N 0
#define WS_C2N 8192
#define WS_BN  16384
#define WS_C1E 24576
#define WS_C2E 57344
#define WS_BE  90112
#define WS_SNW 122880   // node score * mask (8192)
#define WS_SEW 131072   // edge score * keep (32768)
#define WS_KLIST 163840 // int[32768]
#define WS_KCNT 196608  // int[16]
#define WS_SCALE 196624 // float[16]

// output float offsets: xn | L0 | xe | L1
#define O_XN 0
#define O_L0 524288
#define O_XE 4718592
#define O_L1 6815744

// zero-space: float4 indices over concatenated L0 (4,194,304 f) || L1 (67,108,864 f)
#define L04 1048576      // float4 count of L0
#define ZTOT4 17825792   // total float4 to zero (17 per thread at 2048x512)

// ---------------------------------------------------------------------------
// K1: per-row channel dots. One wave per row; c_k = x_row . W_k.
__global__ __launch_bounds__(256) void k_dots(const float* __restrict__ xn,
    const float* __restrict__ xe, const float* __restrict__ Wn,
    const float* __restrict__ We, float* __restrict__ ws) {
  int gw = (blockIdx.x * 256 + threadIdx.x) >> 6;
  int lane = threadIdx.x & 63;
  const float* x; const float* W; int row; float *c1, *c2, *bs;
  if (gw < NNT) {
    row = gw; x = xn + (size_t)row * 64; W = Wn;
    c1 = ws + WS_C1N; c2 = ws + WS_C2N; bs = ws + WS_BN;
  } else {
    row = gw - NNT;
    x = xe + (size_t)row * 64; W = We;
    c1 = ws + WS_C1E; c2 = ws + WS_C2E; bs = ws + WS_BE;
  }
  float v = x[lane];
  float r0 = v * W[lane];
  float r1 = v * W[64 + lane];
  float r2 = v * W[128 + lane];
  for (int o = 32; o; o >>= 1) {
    r0 += __shfl_xor(r0, o, 64);
    r1 += __shfl_xor(r1, o, 64);
    r2 += __shfl_xor(r2, o, 64);
  }
  if (lane == 0) { c1[row] = r1; c2[row] = r2; bs[row] = r0 + r1 + r2; }
}

// ---------------------------------------------------------------------------
// K2 fused: blocks 0..15 = full per-graph pipeline (node msg -> node scores ->
// edge msg -> edge scores -> aug -> rank-based top-256 -> keep/CSR -> power
// iteration -> scale). Blocks 16.. stream-zero L0+L1 (284 MB), hiding the
// latency-bound pooling under pure store bandwidth.
#define SB 3104  // scratch base (floats) inside smem
__global__ __launch_bounds__(512) void k_pool(
    const int* __restrict__ src_n, const int* __restrict__ dst_n, const float* __restrict__ wn,
    const int* __restrict__ src_e, const int* __restrict__ dst_e, const float* __restrict__ we,
    const int* __restrict__ edge_u, const int* __restrict__ edge_v,
    const float* __restrict__ bnp, const float* __restrict__ bep,
    float* __restrict__ ws, float* __restrict__ out) {
  const int tid = threadIdx.x;
  if (blockIdx.x >= 16) {
    // zero-fill: exactly 17 float4 stores per thread, no divergence
    float4 z = make_float4(0.f, 0.f, 0.f, 0.f);
    float4* o4 = (float4*)out;
    int start = (blockIdx.x - 16) * 512 + tid;
    for (int i = start; i < ZTOT4; i += 2048 * 512) {
      int f = (i < L04) ? (O_L0 / 4 + i) : (O_L1 / 4 + (i - L04));
      o4[f] = z;
    }
    return;
  }
  __shared__ float smem[13856];  // 55.4 KB, phase-aliased
  int* smi = (int*)smem;
  // persistent
  float* seS = smem;             // [0,2048)   edge scores
  float* aug = smem + 2048;      // [2048,2560)
  float* snw = smem + 2560;      // [2560,3072) node scores
  float* red = smem + 3072;      // [3072,3080)
  int*   iws = smi + 3080;       // [3080,3088) wave scan sums
  int*   kcp = smi + 3088;       // kcnt
  // msg-node phase scratch (aliases pool scratch)
  float* c1n = smem + SB;        float* c2n = smem + SB + 512;
  float* d1n = smem + SB + 1024; float* d2n = smem + SB + 1536;
  float* e2n = smem + SB + 2048;
  // msg-edge phase scratch
  float* c1e = smem + SB;        float* c2e = smem + SB + 2048;
  float* d1e = smem + SB + 4096; float* d2e = smem + SB + 6144;
  float* e2e = smem + SB + 8192;
  // pool phase scratch
  int* suL  = smi + SB;          int* svL  = smi + SB + 2048;
  int* maskS = smi + SB + 4096;  int* degS = smi + SB + 4608;
  int* offS = smi + SB + 5120;   int* adj  = smi + SB + 5632; // 4096
  float* wvA = smem + SB + 9728; float* wvB = smem + SB + 10240;

  const int g = blockIdx.x;
  const int roffN = g * NNODE;
  const int roffE = g * EEDGE;
  const int lane = tid & 63, wid = tid >> 6;

  // ---- node message passing ----
  if (tid < NNODE) {
    c1n[tid] = ws[WS_C1N + roffN + tid];
    c2n[tid] = ws[WS_C2N + roffN + tid];
    d1n[tid] = 0.f; d2n[tid] = 0.f; e2n[tid] = 0.f;
  }
  __syncthreads();
  for (int t = tid; t < 4096; t += 512) {
    int idx = (t < 2048) ? (g * 2048 + t) : (32768 + g * 2048 + (t - 2048));
    int s = src_n[idx] - roffN, d = dst_n[idx] - roffN;
    float w = wn[idx];
    atomicAdd(&d1n[d], w * c1n[s]);
    atomicAdd(&d2n[d], w * c2n[s]);
  }
  __syncthreads();
  for (int t = tid; t < 4096; t += 512) {
    int idx = (t < 2048) ? (g * 2048 + t) : (32768 + g * 2048 + (t - 2048));
    int s = src_n[idx] - roffN, d = dst_n[idx] - roffN;
    atomicAdd(&e2n[d], wn[idx] * d2n[s]);
  }
  __syncthreads();
  float biasN = bnp[0], biasE = bep[0];
  if (tid < NNODE) {
    float t = ws[WS_BN + roffN + tid] - d1n[tid] - 2.0f * d2n[tid]
            + 0.5f * e2n[tid] + biasN;
    float s = 1.0f / (1.0f + expf(-t));
    snw[tid] = s; aug[tid] = s;
  }
  __syncthreads();

  // ---- edge message passing (clobbers node scratch) ----
  for (int i = tid; i < EEDGE; i += 512) {
    c1e[i] = ws[WS_C1E + roffE + i];
    c2e[i] = ws[WS_C2E + roffE + i];
    d1e[i] = 0.f; d2e[i] = 0.f; e2e[i] = 0.f;
  }
  __syncthreads();
  for (int t = tid; t < 8192; t += 512) {
    int idx = g * 8192 + t;
    int s = src_e[idx] - roffE, d = dst_e[idx] - roffE;
    float w = we[idx];
    atomicAdd(&d1e[d], w * c1e[s]);
    atomicAdd(&d2e[d], w * c2e[s]);
  }
  __syncthreads();
  for (int t = tid; t < 8192; t += 512) {
    int idx = g * 8192 + t;
    int s = src_e[idx] - roffE, d = dst_e[idx] - roffE;
    atomicAdd(&e2e[d], we[idx] * d2e[s]);
  }
  __syncthreads();
  // edge scores + aug scatter (edge_u/v are LOCAL node ids)
  for (int e = tid; e < EEDGE; e += 512) {
    float t = ws[WS_BE + roffE + e] - d1e[e] - 2.0f * d2e[e]
            + 0.5f * e2e[e] + biasE;
    float s = 1.0f / (1.0f + expf(-t));
    seS[e] = s;
    atomicAdd(&aug[edge_u[roffE + e]], s);
    atomicAdd(&aug[edge_v[roffE + e]], s);
  }
  __syncthreads();

  // ---- rank-based top-256 (exact stable argsort(-aug)[:256] semantics) ----
  {
    float a = aug[tid];
    int r = 0;
    #pragma unroll 8
    for (int j = 0; j < NNODE; ++j) {
      float b = aug[j];
      r += (b > a) || (b == a && j < tid);
    }
    maskS[tid] = (r < KEEPN) ? 1 : 0;
    degS[tid] = 0;
  }
  // load su/sv (aliases dead c1e/c2e); write masked node score out
  for (int e = tid; e < EEDGE; e += 512) {
    suL[e] = edge_u[roffE + e];
    svL[e] = edge_v[roffE + e];
  }
  if (tid == 0) *kcp = 0;
  __syncthreads();
  ws[WS_SNW + roffN + tid] = snw[tid] * (float)maskS[tid];

  // ---- keep_e, klist compaction, degree count ----
  int* wsi = (int*)ws;
  for (int e = tid; e < EEDGE; e += 512) {
    int u = suL[e], v = svL[e];
    int k = maskS[u] & maskS[v];
    ws[WS_SEW + roffE + e] = seS[e] * (float)k;
    if (k) {
      int p = atomicAdd(kcp, 1);
      wsi[WS_KLIST + roffE + p] = e;
      atomicAdd(&degS[u], 1);
      atomicAdd(&degS[v], 1);
    }
  }
  __syncthreads();
  if (tid == 0) wsi[WS_KCNT + g] = *kcp;

  // ---- exclusive prefix of deg via wave scan (2 syncs) ----
  int dv = degS[tid];
  int inc = dv;
  for (int o = 1; o < 64; o <<= 1) {
    int t = __shfl_up(inc, o, 64);
    if (lane >= o) inc += t;
  }
  if (lane == 63) iws[wid] = inc;
  __syncthreads();
  int base = 0;
  for (int k = 0; k < wid; ++k) base += iws[k];
  int myStart = base + inc - dv;
  offS[tid] = myStart;
  __syncthreads();

  // ---- CSR fill ----
  for (int e = tid; e < EEDGE; e += 512) {
    int u = suL[e], v = svL[e];
    if (maskS[u] & maskS[v]) {
      int pu = atomicAdd(&offS[u], 1); adj[pu] = v;
      int pv = atomicAdd(&offS[v], 1); adj[pv] = u;
    }
  }
  __syncthreads();
  int myDeg = dv;
  int myEnd = offS[tid];  // == myStart + myDeg

  // ---- power iteration: ping-pong, normalize every 8th iter ----
  wvA[tid] = 0.04419417382415922f; // 1/sqrt(512)
  __syncthreads();
  float* wcur = wvA; float* wnext = wvB;
  for (int it = 0; it < PITERS; ++it) {
    float acc = (float)myDeg * wcur[tid];
    for (int p = myStart; p < myEnd; ++p) acc -= wcur[adj[p]];
    if ((it & 7) == 7) {
      float sq = acc * acc;
      for (int o = 32; o; o >>= 1) sq += __shfl_xor(sq, o, 64);
      if (lane == 0) red[wid] = sq;
      __syncthreads();
      float tot = red[0] + red[1] + red[2] + red[3]
                + red[4] + red[5] + red[6] + red[7];
      wnext[tid] = acc * (1.0f / (sqrtf(tot) + 1e-12f));
    } else {
      wnext[tid] = acc;
    }
    __syncthreads();
    float* tmp = wcur; wcur = wnext; wnext = tmp;
  }
  // ---- Rayleigh quotient (wcur is normalized: iter 63 hit the 8-step) ----
  {
    float wv_ = wcur[tid];
    float acc = (float)myDeg * wv_;
    for (int p = myStart; p < myEnd; ++p) acc -= wcur[adj[p]];
    float pr = wv_ * acc;
    for (int o = 32; o; o >>= 1) pr += __shfl_xor(pr, o, 64);
    if (lane == 0) red[wid] = pr;
    __syncthreads();
    if (tid == 0) {
      float lam = red[0] + red[1] + red[2] + red[3]
                + red[4] + red[5] + red[6] + red[7];
      ws[WS_SCALE + g] = 2.0f / (lam + 1e-12f);
    }
  }
}

// ---------------------------------------------------------------------------
// K3: outputs. [0,512) xn dense; [512,2560) xe dense; [2560,2576) L0 scatter;
// [2576,6672) L1 pair enumeration over compacted kept edges.
__global__ __launch_bounds__(256) void k_out(
    const float* __restrict__ xn, const float* __restrict__ xe,
    const int* __restrict__ edge_u, const int* __restrict__ edge_v,
    const float* __restrict__ ws, float* __restrict__ out) {
  int b = blockIdx.x, tid = threadIdx.x;
  const int* wsi = (const int*)ws;
  if (b < 512) {
    int idx = b * 256 + tid;
    int row = idx >> 4;
    float s = ws[WS_SNW + row];
    float4 x4 = ((const float4*)xn)[idx];
    ((float4*)(out + O_XN))[idx] = make_float4(x4.x * s, x4.y * s, x4.z * s, x4.w * s);
  } else if (b < 2560) {
    int idx = (b - 512) * 256 + tid;
    int row = idx >> 4;
    float s = ws[WS_SEW + row];
    float4 x4 = ((const float4*)xe)[idx];
    ((float4*)(out + O_XE))[idx] = make_float4(x4.x * s, x4.y * s, x4.z * s, x4.w * s);
  } else if (b < 2576) {
    int g = b - 2560;
    int cnt = wsi[WS_KCNT + g];
    float s = ws[WS_SCALE + g];
    float* L0 = out + O_L0 + (long long)g * (NNODE * NNODE);
    const int* kl = wsi + WS_KLIST + g * EEDGE;
    const int* eu = edge_u + g * EEDGE;
    const int* ev = edge_v + g * EEDGE;
    for (int t = tid; t < cnt; t += 256) {
      int e = kl[t];
      int u = eu[e], v = ev[e];
      atomicAdd(&L0[u * NNODE + u], s);
      atomicAdd(&L0[v * NNODE + v], s);
      atomicAdd(&L0[u * NNODE + v], -s);
      atomicAdd(&L0[v * NNODE + u], -s);
    }
  } else {
    int q = b - 2576;
    int g = q >> 8, sb = q & 255;
    int cnt = wsi[WS_KCNT + g];
    float s = ws[WS_SCALE + g];
    float* L1 = out + O_L1 + (long long)g * (EEDGE * EEDGE);
    const int* kl = wsi + WS_KLIST + g * EEDGE;
    const int* eu = edge_u + g * EEDGE;
    const int* ev = edge_v + g * EEDGE;
    for (int a = sb; a < cnt; a += 256) {
      int e1 = kl[a];
      int u1 = eu[e1], v1 = ev[e1];
      long long rowoff = (long long)e1 * EEDGE;
      for (int b2 = tid; b2 < cnt; b2 += 256) {
        int e2 = kl[b2];
        int u2 = eu[e2], v2 = ev[e2];
        int val = (u1 == u2) + (v1 == v2) - (v1 == u2) - (u1 == v2);
        if (val) L1[rowoff + e2] = s * (float)val;
      }
    }
  }
}

// ---------------------------------------------------------------------------
extern "C" void kernel_launch(void* const* d_in, const int* in_sizes, int n_in,
                              void* d_out, int out_size, void* d_ws, size_t ws_size,
                              hipStream_t stream) {
  const float* x_n = (const float*)d_in[0];
  const float* x_e = (const float*)d_in[1];
  const int* edge_u = (const int*)d_in[2];
  const int* edge_v = (const int*)d_in[3];
  const int* src_n = (const int*)d_in[4];
  const int* dst_n = (const int*)d_in[5];
  const float* ew_n = (const float*)d_in[6];
  const int* src_e = (const int*)d_in[7];
  const int* dst_e = (const int*)d_in[8];
  const float* ew_e = (const float*)d_in[9];
  const float* W_n = (const float*)d_in[10];
  const float* b_n = (const float*)d_in[11];
  const float* W_e = (const float*)d_in[12];
  const float* b_e = (const float*)d_in[13];
  float* ws = (float*)d_ws;
  float* out = (float*)d_out;

  // K1: channel dots (exactly 40960 rows, 4 waves/block)
  k_dots<<<10240, 256, 0, stream>>>(x_n, x_e, W_n, W_e, ws);
  // K2: fused msg+scores+pooling (16 blocks) + all 284 MB zero-fill (2048)
  k_pool<<<16 + 2048, 512, 0, stream>>>(src_n, dst_n, ew_n, src_e, dst_e, ew_e,
                                        edge_u, edge_v, b_n, b_e, ws, out);
  // K3: dense xn/xe + sparse L0/L1 scatter
  k_out<<<6672, 256, 0, stream>>>(x_n, x_e, edge_u, edge_v, ws, out);
}

// Round 5
// 470.365 us; speedup vs baseline: 1.0910x; 1.0240x over previous
//
#include <hip/hip_runtime.h>
#include <math.h>

// Problem constants
#define GG 16
#define NNODE 512
#define EEDGE 2048
#define KEEPN 256
#define PITERS 64
#define NNT 8192    // G*N
#define NET 32768   // G*E

typedef float vfloat4 __attribute__((ext_vector_type(4)));  // native vec for nontemporal

// workspace float offsets
#define WS_C1N 0
#define WS_C2N 8192
#define WS_BN  16384
#define WS_C1E 24576
#define WS_C2E 57344
#define WS_BE  90112
#define WS_SNW 122880   // node score * mask (8192)
#define WS_SEW 131072   // edge score * keep (32768)
#define WS_KLIST 163840 // int[32768]
#define WS_KCNT 196608  // int[16]
#define WS_SCALE 196624 // float[16]

// output float offsets: xn | L0 | xe | L1
#define O_XN 0
#define O_L0 524288
#define O_XE 4718592
#define O_L1 6815744

// zero-space: float4 indices over concatenated L0 (4,194,304 f) || L1 (67,108,864 f)
#define L04 1048576      // float4 count of L0
#define ZTOT4 17825792   // total float4 to zero
#define ZA4 6291456      // dots-dispatch covers [0, ZA4): all of L0 + 80 MB of L1
                         // pool-dispatch covers [ZA4, ZTOT4): 176 MB of L1

// ---------------------------------------------------------------------------
// K1: per-row channel dots (one wave per row, blocks < 10240) + zero chunk A.
__global__ __launch_bounds__(256) void k_dots(const float* __restrict__ xn,
    const float* __restrict__ xe, const float* __restrict__ Wn,
    const float* __restrict__ We, float* __restrict__ ws, float* __restrict__ out) {
  if (blockIdx.x >= 10240) {
    vfloat4 z = (vfloat4)(0.f);
    vfloat4* o4 = (vfloat4*)out;
    int start = (blockIdx.x - 10240) * 256 + threadIdx.x;
    #pragma unroll
    for (int n = 0; n < 24; ++n) {        // 1024 blocks x 256 thr x 24 = ZA4 exact
      int i = start + n * 262144;
      int f = (i < L04) ? (O_L0 / 4 + i) : (O_L1 / 4 + (i - L04));
      __builtin_nontemporal_store(z, &o4[f]);
    }
    return;
  }
  int gw = (blockIdx.x * 256 + threadIdx.x) >> 6;
  int lane = threadIdx.x & 63;
  const float* x; const float* W; int row; float *c1, *c2, *bs;
  if (gw < NNT) {
    row = gw; x = xn + (size_t)row * 64; W = Wn;
    c1 = ws + WS_C1N; c2 = ws + WS_C2N; bs = ws + WS_BN;
  } else {
    row = gw - NNT;
    x = xe + (size_t)row * 64; W = We;
    c1 = ws + WS_C1E; c2 = ws + WS_C2E; bs = ws + WS_BE;
  }
  float v = x[lane];
  float r0 = v * W[lane];
  float r1 = v * W[64 + lane];
  float r2 = v * W[128 + lane];
  for (int o = 32; o; o >>= 1) {
    r0 += __shfl_xor(r0, o, 64);
    r1 += __shfl_xor(r1, o, 64);
    r2 += __shfl_xor(r2, o, 64);
  }
  if (lane == 0) { c1[row] = r1; c2[row] = r2; bs[row] = r0 + r1 + r2; }
}

// ---------------------------------------------------------------------------
// K2: blocks 0..15 per-graph pipeline; blocks 16.. zero chunk B (L1 only).
// LDS arena 37 KB (phase-aliased). Power iteration uses register-cached
// adjacency (12 independent LDS gathers, pad -> pinned zero cell wv[512]).
#define SM_AUG 0        // 512 f
#define SM_SNW 512      // 512 f, later reused as offS (int)
#define SM_RED 1024     // 8 f
#define SM_IWS 1032     // 8 int
#define SM_KCP 1040     // 1 int
#define SM_S0  1056     // 8200-float scratch
#define SM_TOT 9256
#define DCAP 12
__global__ __launch_bounds__(512) void k_pool(
    const int* __restrict__ src_n, const int* __restrict__ dst_n, const float* __restrict__ wn,
    const int* __restrict__ src_e, const int* __restrict__ dst_e, const float* __restrict__ we,
    const int* __restrict__ edge_u, const int* __restrict__ edge_v,
    const float* __restrict__ bnp, const float* __restrict__ bep,
    float* __restrict__ ws, float* __restrict__ out) {
  const int tid = threadIdx.x;
  if (blockIdx.x >= 16) {
    vfloat4 z = (vfloat4)(0.f);
    vfloat4* o4 = (vfloat4*)out;
    int start = ZA4 + (blockIdx.x - 16) * 512 + tid;
    #pragma unroll
    for (int n = 0; n < 11; ++n) {        // 2048 x 512 x 11 covers [ZA4,ZTOT4) exact
      int i = start + n * 1048576;
      __builtin_nontemporal_store(z, &o4[O_L1 / 4 + (i - L04)]);
    }
    return;
  }
  __shared__ float smem[SM_TOT];
  int* smi = (int*)smem;
  float* aug = smem + SM_AUG;
  float* snw = smem + SM_SNW;
  float* red = smem + SM_RED;
  int*   iws = smi + SM_IWS;
  int*   kcp = smi + SM_KCP;

  const int g = blockIdx.x;
  const int roffN = g * NNODE;
  const int roffE = g * EEDGE;
  const int lane = tid & 63, wid = tid >> 6;
  float biasN = bnp[0], biasE = bep[0];

  // ---- node message passing (scratch: 5 x 512 at S0) ----
  {
    float* c1n = smem + SM_S0;
    float* c2n = smem + SM_S0 + 512;
    float* d1n = smem + SM_S0 + 1024;
    float* d2n = smem + SM_S0 + 1536;
    float* e2n = smem + SM_S0 + 2048;
    c1n[tid] = ws[WS_C1N + roffN + tid];
    c2n[tid] = ws[WS_C2N + roffN + tid];
    d1n[tid] = 0.f; d2n[tid] = 0.f; e2n[tid] = 0.f;
    __syncthreads();
    for (int t = tid; t < 4096; t += 512) {
      int idx = (t < 2048) ? (g * 2048 + t) : (32768 + g * 2048 + (t - 2048));
      int s = src_n[idx] - roffN, d = dst_n[idx] - roffN;
      float w = wn[idx];
      atomicAdd(&d1n[d], w * c1n[s]);
      atomicAdd(&d2n[d], w * c2n[s]);
    }
    __syncthreads();
    for (int t = tid; t < 4096; t += 512) {
      int idx = (t < 2048) ? (g * 2048 + t) : (32768 + g * 2048 + (t - 2048));
      int s = src_n[idx] - roffN, d = dst_n[idx] - roffN;
      atomicAdd(&e2n[d], wn[idx] * d2n[s]);
    }
    __syncthreads();
    float t = ws[WS_BN + roffN + tid] - d1n[tid] - 2.0f * d2n[tid]
            + 0.5f * e2n[tid] + biasN;
    float s = 1.0f / (1.0f + expf(-t));
    snw[tid] = s; aug[tid] = s;
    __syncthreads();
  }

  // ---- edge message passing ----
  float* seS = smem + SM_S0 + 2048;   // survives into pool phase (old c2e)
  int*   suv = smi + SM_S0;           // packed u|v<<16 (old c1e/e2e, written last)
  {
    float* c1e = smem + SM_S0;
    float* c2e = smem + SM_S0 + 2048;
    float* d1e = smem + SM_S0 + 4096;
    float* d2e = smem + SM_S0 + 6144;
    float* e2e = smem + SM_S0;        // aliases c1e after hop 1
    for (int i = tid; i < EEDGE; i += 512) {
      c1e[i] = ws[WS_C1E + roffE + i];
      c2e[i] = ws[WS_C2E + roffE + i];
      d1e[i] = 0.f; d2e[i] = 0.f;
    }
    __syncthreads();
    for (int t = tid; t < 8192; t += 512) {
      int idx = g * 8192 + t;
      int s = src_e[idx] - roffE, d = dst_e[idx] - roffE;
      float w = we[idx];
      atomicAdd(&d1e[d], w * c1e[s]);
      atomicAdd(&d2e[d], w * c2e[s]);
    }
    __syncthreads();
    for (int i = tid; i < EEDGE; i += 512) e2e[i] = 0.f;
    __syncthreads();
    for (int t = tid; t < 8192; t += 512) {
      int idx = g * 8192 + t;
      int s = src_e[idx] - roffE, d = dst_e[idx] - roffE;
      atomicAdd(&e2e[d], we[idx] * d2e[s]);
    }
    __syncthreads();
    // edge scores + aug scatter + pack u,v (elementwise overwrite of e2e slot)
    for (int e = tid; e < EEDGE; e += 512) {
      float t = ws[WS_BE + roffE + e] - d1e[e] - 2.0f * d2e[e]
              + 0.5f * e2e[e] + biasE;
      float s = 1.0f / (1.0f + expf(-t));
      int u = edge_u[roffE + e], v = edge_v[roffE + e];
      seS[e] = s;                       // seS == c2e slot e (c2 dead)
      suv[e] = u | (v << 16);           // suv == e2e slot e (read before write)
      atomicAdd(&aug[u], s);
      atomicAdd(&aug[v], s);
    }
    __syncthreads();
  }

  // ---- pool-phase scratch ----
  unsigned short* adjU = (unsigned short*)(smem + SM_S0 + 4096); // 4096 ushorts
  float* wvA = smem + SM_S0 + 6144;   // 513 (+pad)
  float* wvB = smem + SM_S0 + 6660;   // 513 (+pad)
  int* maskS = smi + SM_S0 + 7176;
  int* degS  = smi + SM_S0 + 7688;
  int* offS  = smi + SM_SNW;          // reuses snw after SNW written out

  // ---- rank-based top-256 (exact stable argsort(-aug)[:256]) ----
  {
    float a = aug[tid];
    int r = 0;
    #pragma unroll 8
    for (int j = 0; j < NNODE; ++j) {
      float b = aug[j];
      r += (b > a) || (b == a && j < tid);
    }
    maskS[tid] = (r < KEEPN) ? 1 : 0;
    degS[tid] = 0;
  }
  if (tid == 0) *kcp = 0;
  __syncthreads();
  ws[WS_SNW + roffN + tid] = snw[tid] * (float)maskS[tid];

  // ---- keep_e, klist compaction, degree count ----
  int* wsi = (int*)ws;
  for (int e = tid; e < EEDGE; e += 512) {
    int p2 = suv[e];
    int u = p2 & 0xffff, v = p2 >> 16;
    int k = maskS[u] & maskS[v];
    ws[WS_SEW + roffE + e] = seS[e] * (float)k;
    if (k) {
      int p = atomicAdd(kcp, 1);
      wsi[WS_KLIST + roffE + p] = e;
      atomicAdd(&degS[u], 1);
      atomicAdd(&degS[v], 1);
    }
  }
  __syncthreads();
  if (tid == 0) wsi[WS_KCNT + g] = *kcp;

  // ---- exclusive prefix of deg via wave scan ----
  int dv = degS[tid];
  int inc = dv;
  for (int o = 1; o < 64; o <<= 1) {
    int t = __shfl_up(inc, o, 64);
    if (lane >= o) inc += t;
  }
  if (lane == 63) iws[wid] = inc;
  __syncthreads();
  int base = 0;
  for (int k = 0; k < wid; ++k) base += iws[k];
  int myStart = base + inc - dv;
  offS[tid] = myStart;
  __syncthreads();

  // ---- CSR fill (ushort adjacency) ----
  for (int e = tid; e < EEDGE; e += 512) {
    int p2 = suv[e];
    int u = p2 & 0xffff, v = p2 >> 16;
    if (maskS[u] & maskS[v]) {
      int pu = atomicAdd(&offS[u], 1); adjU[pu] = (unsigned short)v;
      int pv = atomicAdd(&offS[v], 1); adjU[pv] = (unsigned short)u;
    }
  }
  __syncthreads();
  int myDeg = dv;
  int myEnd = myStart + myDeg;

  // ---- register-cached adjacency (pad -> pinned zero cell 512) ----
  int nbr[DCAP];
  #pragma unroll
  for (int k = 0; k < DCAP; ++k)
    nbr[k] = (k < myDeg) ? (int)adjU[myStart + k] : NNODE;
  bool ovf = myDeg > DCAP;

  wvA[tid] = 0.04419417382415922f; // 1/sqrt(512)
  if (tid == 0) { wvA[NNODE] = 0.f; wvB[NNODE] = 0.f; }
  __syncthreads();
  float* wcur = wvA; float* wnext = wvB;
  for (int it = 0; it < PITERS; ++it) {
    float acc = (float)myDeg * wcur[tid];
    #pragma unroll
    for (int k = 0; k < DCAP; ++k) acc -= wcur[nbr[k]];
    if (ovf) for (int p = myStart + DCAP; p < myEnd; ++p) acc -= wcur[(int)adjU[p]];
    if ((it & 7) == 7) {
      float sq = acc * acc;
      for (int o = 32; o; o >>= 1) sq += __shfl_xor(sq, o, 64);
      if (lane == 0) red[wid] = sq;
      __syncthreads();
      float tot = red[0] + red[1] + red[2] + red[3]
                + red[4] + red[5] + red[6] + red[7];
      wnext[tid] = acc * (1.0f / (sqrtf(tot) + 1e-12f));
    } else {
      wnext[tid] = acc;
    }
    __syncthreads();
    float* tmp = wcur; wcur = wnext; wnext = tmp;
  }
  // ---- Rayleigh quotient (iter 63 normalized) ----
  {
    float wv_ = wcur[tid];
    float acc = (float)myDeg * wv_;
    #pragma unroll
    for (int k = 0; k < DCAP; ++k) acc -= wcur[nbr[k]];
    if (ovf) for (int p = myStart + DCAP; p < myEnd; ++p) acc -= wcur[(int)adjU[p]];
    float pr = wv_ * acc;
    for (int o = 32; o; o >>= 1) pr += __shfl_xor(pr, o, 64);
    if (lane == 0) red[wid] = pr;
    __syncthreads();
    if (tid == 0) {
      float lam = red[0] + red[1] + red[2] + red[3]
                + red[4] + red[5] + red[6] + red[7];
      ws[WS_SCALE + g] = 2.0f / (lam + 1e-12f);
    }
  }
}

// ---------------------------------------------------------------------------
// K3: outputs. [0,512) xn dense; [512,2560) xe dense; [2560,2576) L0 scatter;
// [2576,6672) L1 pair enumeration over compacted kept edges.
__global__ __launch_bounds__(256) void k_out(
    const float* __restrict__ xn, const float* __restrict__ xe,
    const int* __restrict__ edge_u, const int* __restrict__ edge_v,
    const float* __restrict__ ws, float* __restrict__ out) {
  int b = blockIdx.x, tid = threadIdx.x;
  const int* wsi = (const int*)ws;
  if (b < 512) {
    int idx = b * 256 + tid;
    int row = idx >> 4;
    float s = ws[WS_SNW + row];
    float4 x4 = ((const float4*)xn)[idx];
    ((float4*)(out + O_XN))[idx] = make_float4(x4.x * s, x4.y * s, x4.z * s, x4.w * s);
  } else if (b < 2560) {
    int idx = (b - 512) * 256 + tid;
    int row = idx >> 4;
    float s = ws[WS_SEW + row];
    float4 x4 = ((const float4*)xe)[idx];
    ((float4*)(out + O_XE))[idx] = make_float4(x4.x * s, x4.y * s, x4.z * s, x4.w * s);
  } else if (b < 2576) {
    int g = b - 2560;
    int cnt = wsi[WS_KCNT + g];
    float s = ws[WS_SCALE + g];
    float* L0 = out + O_L0 + (long long)g * (NNODE * NNODE);
    const int* kl = wsi + WS_KLIST + g * EEDGE;
    const int* eu = edge_u + g * EEDGE;
    const int* ev = edge_v + g * EEDGE;
    for (int t = tid; t < cnt; t += 256) {
      int e = kl[t];
      int u = eu[e], v = ev[e];
      atomicAdd(&L0[u * NNODE + u], s);
      atomicAdd(&L0[v * NNODE + v], s);
      atomicAdd(&L0[u * NNODE + v], -s);
      atomicAdd(&L0[v * NNODE + u], -s);
    }
  } else {
    int q = b - 2576;
    int g = q >> 8, sb = q & 255;
    int cnt = wsi[WS_KCNT + g];
    float s = ws[WS_SCALE + g];
    float* L1 = out + O_L1 + (long long)g * (EEDGE * EEDGE);
    const int* kl = wsi + WS_KLIST + g * EEDGE;
    const int* eu = edge_u + g * EEDGE;
    const int* ev = edge_v + g * EEDGE;
    for (int a = sb; a < cnt; a += 256) {
      int e1 = kl[a];
      int u1 = eu[e1], v1 = ev[e1];
      long long rowoff = (long long)e1 * EEDGE;
      for (int b2 = tid; b2 < cnt; b2 += 256) {
        int e2 = kl[b2];
        int u2 = eu[e2], v2 = ev[e2];
        int val = (u1 == u2) + (v1 == v2) - (v1 == u2) - (u1 == v2);
        if (val) L1[rowoff + e2] = s * (float)val;
      }
    }
  }
}

// ---------------------------------------------------------------------------
extern "C" void kernel_launch(void* const* d_in, const int* in_sizes, int n_in,
                              void* d_out, int out_size, void* d_ws, size_t ws_size,
                              hipStream_t stream) {
  const float* x_n = (const float*)d_in[0];
  const float* x_e = (const float*)d_in[1];
  const int* edge_u = (const int*)d_in[2];
  const int* edge_v = (const int*)d_in[3];
  const int* src_n = (const int*)d_in[4];
  const int* dst_n = (const int*)d_in[5];
  const float* ew_n = (const float*)d_in[6];
  const int* src_e = (const int*)d_in[7];
  const int* dst_e = (const int*)d_in[8];
  const float* ew_e = (const float*)d_in[9];
  const float* W_n = (const float*)d_in[10];
  const float* b_n = (const float*)d_in[11];
  const float* W_e = (const float*)d_in[12];
  const float* b_e = (const float*)d_in[13];
  float* ws = (float*)d_ws;
  float* out = (float*)d_out;

  // A: channel dots (10240 blocks) + zero chunk A (1024 blocks, 96 MB)
  k_dots<<<10240 + 1024, 256, 0, stream>>>(x_n, x_e, W_n, W_e, ws, out);
  // B: fused msg+scores+pooling (16) + zero chunk B (2048 blocks, 176 MB)
  k_pool<<<16 + 2048, 512, 0, stream>>>(src_n, dst_n, ew_n, src_e, dst_e, ew_e,
                                        edge_u, edge_v, b_n, b_e, ws, out);
  // C: dense xn/xe + sparse L0/L1 scatter
  k_out<<<6672, 256, 0, stream>>>(x_n, x_e, edge_u, edge_v, ws, out);
}